// Round 4
// baseline (15914.648 us; speedup 1.0000x reference)
//
#include <hip/hip_runtime.h>
#include <math.h>

#define B_    32
#define S_    512
#define EMB_  512
#define HID_  1024
#define LAB_  64
#define M_    (B_ * S_)

// ---------------------------------------------------------------------------
// Sync state: device globals, zero-init at module load; every scan launch
// returns them to 0 (ack-based reset) so fresh launches and graph replays
// always start clean. One 64B line per flag so 32 producers store in parallel.
// ---------------------------------------------------------------------------
struct PadFlag { unsigned v; unsigned pad[15]; };   // 64 B
struct PadCnt  { unsigned v; unsigned pad[63]; };   // 256 B
__device__ PadFlag g_flag[8][32];
__device__ PadCnt  g_ack[8];

__device__ __forceinline__ float aload(const float* p) {
    return __hip_atomic_load((float*)p, __ATOMIC_RELAXED, __HIP_MEMORY_SCOPE_AGENT);
}
__device__ __forceinline__ void astore(float* p, float v) {
    __hip_atomic_store(p, v, __ATOMIC_RELAXED, __HIP_MEMORY_SCOPE_AGENT);
}

// ---------------------------------------------------------------------------
// fp32 tiled GEMM with optional row-gather on A (unchanged from R3):
//   C[m][n] = dot(Arow(m), W[n][:]) + bias[n] (+ bias2[n]),  W row-major [N,K]
// ---------------------------------------------------------------------------
__global__ __launch_bounds__(256) void gemm_bias(
    const float* __restrict__ A, const int* __restrict__ tokens,
    const float* __restrict__ W, const float* __restrict__ bias,
    const float* __restrict__ bias2, float* __restrict__ C,
    int M, int K, int N)
{
    __shared__ float As[64][17];
    __shared__ float Ws[64][17];

    const int tid = threadIdx.x;
    const int tx  = tid & 15;
    const int ty  = tid >> 4;
    const int n0  = blockIdx.x * 64;
    const int m0  = blockIdx.y * 64;

    const int lrow = tid >> 2;
    const int lk   = (tid & 3) << 2;

    const int arow_idx = tokens ? tokens[m0 + lrow] : (m0 + lrow);
    const float* __restrict__ arow = A + (size_t)arow_idx * K;
    const float* __restrict__ wrow = W + (size_t)(n0 + lrow) * K;

    float bs[4];
#pragma unroll
    for (int j = 0; j < 4; ++j) {
        int n = n0 + tx * 4 + j;
        bs[j] = bias[n] + (bias2 ? bias2[n] : 0.0f);
    }

    float acc[4][4] = {};

    for (int k0 = 0; k0 < K; k0 += 16) {
        const float4 av = *(const float4*)(arow + k0 + lk);
        const float4 wv = *(const float4*)(wrow + k0 + lk);
        __syncthreads();
        As[lrow][lk + 0] = av.x; As[lrow][lk + 1] = av.y;
        As[lrow][lk + 2] = av.z; As[lrow][lk + 3] = av.w;
        Ws[lrow][lk + 0] = wv.x; Ws[lrow][lk + 1] = wv.y;
        Ws[lrow][lk + 2] = wv.z; Ws[lrow][lk + 3] = wv.w;
        __syncthreads();

#pragma unroll
        for (int kk = 0; kk < 16; ++kk) {
            float a[4], b[4];
#pragma unroll
            for (int i = 0; i < 4; ++i) a[i] = As[ty * 4 + i][kk];
#pragma unroll
            for (int j = 0; j < 4; ++j) b[j] = Ws[tx * 4 + j][kk];
#pragma unroll
            for (int i = 0; i < 4; ++i)
#pragma unroll
                for (int j = 0; j < 4; ++j)
                    acc[i][j] += a[i] * b[j];
        }
    }

#pragma unroll
    for (int i = 0; i < 4; ++i) {
        const int m = m0 + ty * 4 + i;
        float4 v;
        v.x = acc[i][0] + bs[0];
        v.y = acc[i][1] + bs[1];
        v.z = acc[i][2] + bs[2];
        v.w = acc[i][3] + bs[3];
        *(float4*)(C + (size_t)m * N + n0 + tx * 4) = v;
    }
}

// ---------------------------------------------------------------------------
// Weight-stationary persistent scan, R4: W_hh in REGISTERS (128 VGPR/thread),
// LDS only for the staged h (swizzle-padded), parallel flag barrier,
// shfl_xor k-reduction. 256 WGs (32 slices x 8 XCD-affine batch groups),
// 1 WG/CU forced via 96 KB dynamic-LDS request. In place: x = xp in, h out.
// Thread (jg=tid>>5, kg=tid&31): neurons s*32+jg*4..+3, k-chunk kg*32..+31.
// ---------------------------------------------------------------------------
#define HSTR 1152   // per-batch LDS floats: 32 kg-chunks * 36 (32 data + 4 pad)

__global__ __launch_bounds__(256, 1) void rnn_scan_reg(
    const float* __restrict__ Whh,   // [H][H] row-major (original layout)
    float* __restrict__ x)           // [B,S,H]
{
    extern __shared__ float hl[];    // 4 * HSTR floats = 18432 B used

    const int wg  = blockIdx.x;
    const int bg  = wg & 7;          // batch group (XCD-affine)
    const int s   = wg >> 3;         // neuron slice
    const int tid = threadIdx.x;
    const int jg  = tid >> 5;        // 0..7
    const int kg  = tid & 31;        // 0..31
    const int b0  = bg * 4;
    const int sb  = tid >> 6;        // staging batch 0..3
    const int sk  = tid & 63;        // staging float4-chunk base

    // --- weights into registers: 4 neurons x 32 k-values = 128 VGPRs ---
    float4 wreg[4][8];
    {
        const float* wbase = Whh + (size_t)(s * 32 + jg * 4) * HID_ + kg * 32;
#pragma unroll
        for (int i = 0; i < 4; ++i)
#pragma unroll
            for (int q = 0; q < 8; ++q)
                wreg[i][q] = *(const float4*)(wbase + (size_t)i * HID_ + q * 4);
    }

    unsigned* myflag = &g_flag[bg][s].v;

    for (int t = 0; t < S_; ++t) {
        // ---- wait for h_{t-1} (parallel flag poll), then stage into LDS ----
        if (t > 0) {
            if (tid < 64) {
                const bool need = tid < 32;
                unsigned* fp = &g_flag[bg][tid & 31].v;
                for (;;) {
                    unsigned v = need
                        ? __hip_atomic_load(fp, __ATOMIC_ACQUIRE, __HIP_MEMORY_SCOPE_AGENT)
                        : 0xffffffffu;
                    if (!__ballot(need && (v < (unsigned)t))) break;
                }
            }
            __syncthreads();   // flags seen by all; prev-step hl reads done
            const float* hsrc = x + ((size_t)(b0 + sb) * S_ + (t - 1)) * HID_;
#pragma unroll
            for (int q = 0; q < 4; ++q) {
                const int kf = sk + q * 64;            // float4 index 0..255
                float4 v;
                v.x = aload(hsrc + 4 * kf + 0);
                v.y = aload(hsrc + 4 * kf + 1);
                v.z = aload(hsrc + 4 * kf + 2);
                v.w = aload(hsrc + 4 * kf + 3);
                *(float4*)(hl + sb * HSTR + (kf >> 3) * 36 + (kf & 7) * 4) = v;
            }
        } else {
#pragma unroll
            for (int q = 0; q < 4; ++q) {
                const int kf = sk + q * 64;
                *(float4*)(hl + sb * HSTR + (kf >> 3) * 36 + (kf & 7) * 4) =
                    make_float4(0.f, 0.f, 0.f, 0.f);
            }
        }
        __syncthreads();

        // ---- partial dot products: 4 neurons x 4 batches over k-chunk ----
        float acc[4][4] = {};
#pragma unroll
        for (int q = 0; q < 8; ++q) {
            float4 hv[4];
#pragma unroll
            for (int b = 0; b < 4; ++b)
                hv[b] = *(const float4*)(hl + b * HSTR + kg * 36 + q * 4);
#pragma unroll
            for (int i = 0; i < 4; ++i)
#pragma unroll
                for (int b = 0; b < 4; ++b)
                    acc[i][b] += wreg[i][q].x * hv[b].x + wreg[i][q].y * hv[b].y
                               + wreg[i][q].z * hv[b].z + wreg[i][q].w * hv[b].w;
        }

        // ---- reduce over kg: width-32 butterfly (lanes are contiguous) ----
#pragma unroll
        for (int m = 1; m < 32; m <<= 1)
#pragma unroll
            for (int i = 0; i < 4; ++i)
#pragma unroll
                for (int b = 0; b < 4; ++b)
                    acc[i][b] += __shfl_xor(acc[i][b], m, 32);

        // ---- lanes kg<16 write the 16 (neuron,batch) outputs ----
        if (kg < 16) {
            const int i = kg >> 2, b = kg & 3;
            float* px = x + ((size_t)(b0 + b) * S_ + t) * HID_ + s * 32 + jg * 4 + i;
            const float xp = *px;                 // xp from prior GEMM
            astore(px, tanhf(xp + acc[i][b]));    // h_t, agent-visible
        }
        __syncthreads();   // drains all waves' stores (vmcnt) before flag
        if (tid == 0 && t < S_ - 1)
            __hip_atomic_store(myflag, (unsigned)(t + 1),
                               __ATOMIC_RELEASE, __HIP_MEMORY_SCOPE_AGENT);
    }

    // ---- epilogue: ack, then slice 0 resets all group state to 0 ----
    __syncthreads();
    if (tid == 0) {
        __hip_atomic_fetch_add(&g_ack[bg].v, 1u, __ATOMIC_ACQ_REL,
                               __HIP_MEMORY_SCOPE_AGENT);
        if (s == 0) {
            while (__hip_atomic_load(&g_ack[bg].v, __ATOMIC_ACQUIRE,
                                     __HIP_MEMORY_SCOPE_AGENT) < 32u)
                __builtin_amdgcn_s_sleep(1);
            for (int i2 = 0; i2 < 32; ++i2)
                __hip_atomic_store(&g_flag[bg][i2].v, 0u,
                                   __ATOMIC_RELAXED, __HIP_MEMORY_SCOPE_AGENT);
            __hip_atomic_store(&g_ack[bg].v, 0u,
                               __ATOMIC_RELEASE, __HIP_MEMORY_SCOPE_AGENT);
        }
    }
}

__global__ __launch_bounds__(256) void copy4(
    const float4* __restrict__ src, float4* __restrict__ dst, int n4)
{
    const int i = blockIdx.x * 256 + threadIdx.x;
    if (i < n4) dst[i] = src[i];
}

extern "C" void kernel_launch(void* const* d_in, const int* in_sizes, int n_in,
                              void* d_out, int out_size, void* d_ws, size_t ws_size,
                              hipStream_t stream)
{
    const int*   tokens = (const int*)  d_in[0];
    const float* emb    = (const float*)d_in[1];
    const float* W_ih0  = (const float*)d_in[2];
    const float* W_hh0  = (const float*)d_in[3];
    const float* b_ih0  = (const float*)d_in[4];
    const float* b_hh0  = (const float*)d_in[5];
    const float* W_ih1  = (const float*)d_in[6];
    const float* W_hh1  = (const float*)d_in[7];
    const float* b_ih1  = (const float*)d_in[8];
    const float* b_hh1  = (const float*)d_in[9];
    const float* W_out  = (const float*)d_in[10];
    const float* b_out  = (const float*)d_in[11];
    float* out = (float*)d_out;

    float* buf = (float*)d_ws;    // ONE [B,S,H] fp32 buffer (64 MiB)
    float* tmp = (float*)d_out;   // 4 MiB xp1 chunk bounce (rewritten by step 5)

    // >80 KiB dynamic LDS forces exactly 1 WG/CU (uniform 256-on-256 placement)
    const size_t scan_lds = 98304;
    hipFuncSetAttribute((const void*)rnn_scan_reg,
                        hipFuncAttributeMaxDynamicSharedMemorySize, (int)scan_lds);

    // 1) xp0 = gather(emb,tokens) @ W_ih0^T + b_ih0 + b_hh0  -> buf
    gemm_bias<<<dim3(HID_ / 64, M_ / 64), 256, 0, stream>>>(
        emb, tokens, W_ih0, b_ih0, b_hh0, buf, M_, EMB_, HID_);

    // 2) layer-0 scan (in place on buf)
    rnn_scan_reg<<<256, 256, scan_lds, stream>>>(W_hh0, buf);

    // 3) xp1 = h0 @ W_ih1^T + b_ih1 + b_hh1, chunked through d_out
    for (int c = 0; c < 16; ++c) {
        const float* Ac = buf + (size_t)c * 1024 * HID_;
        gemm_bias<<<dim3(HID_ / 64, 1024 / 64), 256, 0, stream>>>(
            Ac, nullptr, W_ih1, b_ih1, b_hh1, tmp, 1024, HID_, HID_);
        copy4<<<1024, 256, 0, stream>>>(
            (const float4*)tmp, (float4*)(buf + (size_t)c * 1024 * HID_),
            1024 * HID_ / 4);
    }

    // 4) layer-1 scan
    rnn_scan_reg<<<256, 256, scan_lds, stream>>>(W_hh1, buf);

    // 5) out = h1 @ W_out^T + b_out (fully rewrites d_out)
    gemm_bias<<<dim3(LAB_ / 64, M_ / 64), 256, 0, stream>>>(
        buf, nullptr, W_out, b_out, nullptr, out, M_, HID_, LAB_);
}

// Round 5
// 8894.744 us; speedup vs baseline: 1.7892x; 1.7892x over previous
//
#include <hip/hip_runtime.h>
#include <math.h>

#define B_    32
#define S_    512
#define EMB_  512
#define HID_  1024
#define LAB_  64
#define M_    (B_ * S_)

// ---------------------------------------------------------------------------
// Sync state: device globals, zero-init at load; every scan launch returns
// them to 0 (ack-based reset) so fresh launches / graph replays start clean.
// ---------------------------------------------------------------------------
struct PadFlag { unsigned v; unsigned pad[15]; };   // 64 B
struct PadCnt  { unsigned v; unsigned pad[63]; };   // 256 B
__device__ PadFlag g_flag[8][32];
__device__ PadCnt  g_ack[8];

__device__ __forceinline__ float aload(const float* p) {
    return __hip_atomic_load((float*)p, __ATOMIC_RELAXED, __HIP_MEMORY_SCOPE_AGENT);
}
__device__ __forceinline__ void astore(float* p, float v) {
    __hip_atomic_store(p, v, __ATOMIC_RELAXED, __HIP_MEMORY_SCOPE_AGENT);
}

// ---------------------------------------------------------------------------
// fp32 tiled GEMM with optional row-gather on A (unchanged, known-good):
//   C[m][n] = dot(Arow(m), W[n][:]) + bias[n] (+ bias2[n]),  W row-major [N,K]
// ---------------------------------------------------------------------------
__global__ __launch_bounds__(256) void gemm_bias(
    const float* __restrict__ A, const int* __restrict__ tokens,
    const float* __restrict__ W, const float* __restrict__ bias,
    const float* __restrict__ bias2, float* __restrict__ C,
    int M, int K, int N)
{
    __shared__ float As[64][17];
    __shared__ float Ws[64][17];

    const int tid = threadIdx.x;
    const int tx  = tid & 15;
    const int ty  = tid >> 4;
    const int n0  = blockIdx.x * 64;
    const int m0  = blockIdx.y * 64;

    const int lrow = tid >> 2;
    const int lk   = (tid & 3) << 2;

    const int arow_idx = tokens ? tokens[m0 + lrow] : (m0 + lrow);
    const float* __restrict__ arow = A + (size_t)arow_idx * K;
    const float* __restrict__ wrow = W + (size_t)(n0 + lrow) * K;

    float bs[4];
#pragma unroll
    for (int j = 0; j < 4; ++j) {
        int n = n0 + tx * 4 + j;
        bs[j] = bias[n] + (bias2 ? bias2[n] : 0.0f);
    }

    float acc[4][4] = {};

    for (int k0 = 0; k0 < K; k0 += 16) {
        const float4 av = *(const float4*)(arow + k0 + lk);
        const float4 wv = *(const float4*)(wrow + k0 + lk);
        __syncthreads();
        As[lrow][lk + 0] = av.x; As[lrow][lk + 1] = av.y;
        As[lrow][lk + 2] = av.z; As[lrow][lk + 3] = av.w;
        Ws[lrow][lk + 0] = wv.x; Ws[lrow][lk + 1] = wv.y;
        Ws[lrow][lk + 2] = wv.z; Ws[lrow][lk + 3] = wv.w;
        __syncthreads();

#pragma unroll
        for (int kk = 0; kk < 16; ++kk) {
            float a[4], b[4];
#pragma unroll
            for (int i = 0; i < 4; ++i) a[i] = As[ty * 4 + i][kk];
#pragma unroll
            for (int j = 0; j < 4; ++j) b[j] = Ws[tx * 4 + j][kk];
#pragma unroll
            for (int i = 0; i < 4; ++i)
#pragma unroll
                for (int j = 0; j < 4; ++j)
                    acc[i][j] += a[i] * b[j];
        }
    }

#pragma unroll
    for (int i = 0; i < 4; ++i) {
        const int m = m0 + ty * 4 + i;
        float4 v;
        v.x = acc[i][0] + bs[0];
        v.y = acc[i][1] + bs[1];
        v.z = acc[i][2] + bs[2];
        v.w = acc[i][3] + bs[3];
        *(float4*)(C + (size_t)m * N + n0 + tx * 4) = v;
    }
}

// ---------------------------------------------------------------------------
// Weight-stationary persistent scan, R5.
// 256 WGs x 512 threads, 1 WG/CU (96 KB dyn LDS). WG = slice s (32 neurons)
// x batch group bg (4 batches). Weights in registers: 64 scalars/thread
// (4 neurons x 16 strided k: k = kg + 64q). LDS h is batch-transposed:
// hl4[k] = {h[b0][k],h[b1][k],h[b2][k],h[b3][k]} -> all LDS access patterns
// are lane-contiguous (conflict-free). Split-k (64-way) reduced through LDS.
// In place: x = xp on entry, h on exit.
// ---------------------------------------------------------------------------
#define RPAD 68   // red row stride in floats (272 B = 17*16 B: b128-aligned)

__global__ __launch_bounds__(512, 2) void rnn_scan_reg2(
    const float* __restrict__ Whh,   // [H][H] row-major
    float* __restrict__ x)           // [B,S,H]
{
    extern __shared__ float smem[];
    float4* hl4 = (float4*)smem;              // 1024 float4 = 16 KB
    float*  red = smem + 4 * HID_;            // 128 rows x RPAD = 34.8 KB

    const int wg  = blockIdx.x;
    const int bg  = wg & 7;          // batch group (XCD-affine-ish)
    const int s   = wg >> 3;         // neuron slice 0..31
    const int tid = threadIdx.x;     // 0..511
    const int j8  = tid >> 6;        // 0..7 -> neurons s*32 + j8*4 ..+3
    const int kg  = tid & 63;        // k = kg + 64q
    const int b0  = bg * 4;

    // --- weights into registers: 4 neurons x 16 strided k = 64 VGPRs ---
    float wreg[4][16];
    {
        const float* wb = Whh + (size_t)(s * 32 + j8 * 4) * HID_ + kg;
#pragma unroll
        for (int i = 0; i < 4; ++i)
#pragma unroll
            for (int q = 0; q < 16; ++q)
                wreg[i][q] = wb[(size_t)i * HID_ + q * 64];   // lane-coalesced
    }

    unsigned* myflag = &g_flag[bg][s].v;

    for (int t = 0; t < S_; ++t) {
        // ---- wait for all 32 slices' h_{t-1} (parallel flag poll) ----
        if (t > 0) {
            if (tid < 64) {
                const bool need = tid < 32;
                unsigned* fp = &g_flag[bg][tid & 31].v;
                for (;;) {
                    unsigned v = need
                        ? __hip_atomic_load(fp, __ATOMIC_ACQUIRE, __HIP_MEMORY_SCOPE_AGENT)
                        : 0xffffffffu;
                    if (!__ballot(need && (v < (unsigned)t))) break;
                }
            }
        }
        __syncthreads();   // gate staging on poll; prev-step hl reads done

        // ---- stage h_{t-1} into LDS, batch-transposed ----
        if (t > 0) {
            const float* hbase = x + ((size_t)b0 * S_ + (t - 1)) * HID_;
#pragma unroll
            for (int c = 0; c < 2; ++c) {
                const int m = tid + 512 * c;           // k index, lane-contig
                float4 v;
                v.x = aload(hbase + 0 * S_ * HID_ + m);  // coalesced per batch
                v.y = aload(hbase + 1 * S_ * HID_ + m);
                v.z = aload(hbase + 2 * S_ * HID_ + m);
                v.w = aload(hbase + 3 * S_ * HID_ + m);
                hl4[m] = v;                            // contiguous b128: free
            }
        } else {
#pragma unroll
            for (int c = 0; c < 2; ++c)
                hl4[tid + 512 * c] = make_float4(0.f, 0.f, 0.f, 0.f);
        }
        __syncthreads();

        // ---- partials: 4 neurons x 4 batches over 16 strided k ----
        float acc[4][4] = {};
#pragma unroll
        for (int q = 0; q < 16; ++q) {
            const float4 hv = hl4[kg + 64 * q];        // lane-contig: free
#pragma unroll
            for (int i = 0; i < 4; ++i) {
                const float w = wreg[i][q];
                acc[i][0] += w * hv.x;
                acc[i][1] += w * hv.y;
                acc[i][2] += w * hv.z;
                acc[i][3] += w * hv.w;
            }
        }

        // ---- write partials: red[o][kg], o = (j8*4+i)*4+b ----
#pragma unroll
        for (int i = 0; i < 4; ++i)
#pragma unroll
            for (int b = 0; b < 4; ++b)
                red[((j8 * 4 + i) * 4 + b) * RPAD + kg] = acc[i][b];  // contig: free
        __syncthreads();

        // ---- 2 waves reduce 64 partials each; write h_t ----
        if (tid < 128) {
            const int o = tid;                    // (jl = o>>2, b = o&3)
            const float4* rp = (const float4*)(red + (size_t)o * RPAD);
            float4 r0 = rp[0], r1 = rp[1], r2 = rp[2],  r3 = rp[3];
            float4 r4 = rp[4], r5 = rp[5], r6 = rp[6],  r7 = rp[7];
            float4 r8 = rp[8], r9 = rp[9], ra = rp[10], rb = rp[11];
            float4 rc = rp[12], rd = rp[13], re = rp[14], rf = rp[15];
            float sum = (((r0.x+r0.y+r0.z+r0.w) + (r1.x+r1.y+r1.z+r1.w))
                       + ((r2.x+r2.y+r2.z+r2.w) + (r3.x+r3.y+r3.z+r3.w)))
                      + (((r4.x+r4.y+r4.z+r4.w) + (r5.x+r5.y+r5.z+r5.w))
                       + ((r6.x+r6.y+r6.z+r6.w) + (r7.x+r7.y+r7.z+r7.w)))
                      + (((r8.x+r8.y+r8.z+r8.w) + (r9.x+r9.y+r9.z+r9.w))
                       + ((ra.x+ra.y+ra.z+ra.w) + (rb.x+rb.y+rb.z+rb.w)))
                      + (((rc.x+rc.y+rc.z+rc.w) + (rd.x+rd.y+rd.z+rd.w))
                       + ((re.x+re.y+re.z+re.w) + (rf.x+rf.y+rf.z+rf.w)));
            const int jl = o >> 2, b = o & 3;
            float* px = x + ((size_t)(b0 + b) * S_ + t) * HID_ + s * 32 + jl;
            const float xp = *px;                // xp from prior GEMM
            astore(px, tanhf(xp + sum));         // h_t, device-visible
        }
        __syncthreads();   // drain stores (vmcnt) before signaling
        if (tid == 0 && t < S_ - 1)
            __hip_atomic_store(myflag, (unsigned)(t + 1),
                               __ATOMIC_RELEASE, __HIP_MEMORY_SCOPE_AGENT);
    }

    // ---- epilogue: ack, then slice 0 resets group state to 0 ----
    if (tid == 0) {
        __hip_atomic_fetch_add(&g_ack[bg].v, 1u, __ATOMIC_ACQ_REL,
                               __HIP_MEMORY_SCOPE_AGENT);
        if (s == 0) {
            while (__hip_atomic_load(&g_ack[bg].v, __ATOMIC_ACQUIRE,
                                     __HIP_MEMORY_SCOPE_AGENT) < 32u)
                __builtin_amdgcn_s_sleep(1);
            for (int i2 = 0; i2 < 32; ++i2)
                __hip_atomic_store(&g_flag[bg][i2].v, 0u,
                                   __ATOMIC_RELAXED, __HIP_MEMORY_SCOPE_AGENT);
            __hip_atomic_store(&g_ack[bg].v, 0u,
                               __ATOMIC_RELEASE, __HIP_MEMORY_SCOPE_AGENT);
        }
    }
}

__global__ __launch_bounds__(256) void copy4(
    const float4* __restrict__ src, float4* __restrict__ dst, int n4)
{
    const int i = blockIdx.x * 256 + threadIdx.x;
    if (i < n4) dst[i] = src[i];
}

extern "C" void kernel_launch(void* const* d_in, const int* in_sizes, int n_in,
                              void* d_out, int out_size, void* d_ws, size_t ws_size,
                              hipStream_t stream)
{
    const int*   tokens = (const int*)  d_in[0];
    const float* emb    = (const float*)d_in[1];
    const float* W_ih0  = (const float*)d_in[2];
    const float* W_hh0  = (const float*)d_in[3];
    const float* b_ih0  = (const float*)d_in[4];
    const float* b_hh0  = (const float*)d_in[5];
    const float* W_ih1  = (const float*)d_in[6];
    const float* W_hh1  = (const float*)d_in[7];
    const float* b_ih1  = (const float*)d_in[8];
    const float* b_hh1  = (const float*)d_in[9];
    const float* W_out  = (const float*)d_in[10];
    const float* b_out  = (const float*)d_in[11];
    float* out = (float*)d_out;

    const size_t BUF = (size_t)B_ * S_ * HID_;   // 16M floats = 64 MiB
    float* buf  = (float*)d_ws;
    float* buf1 = buf + BUF;                     // only if ws_size permits
    float* tmp  = (float*)d_out;                 // 4 MiB chunk bounce

    const int two_buf = (ws_size >= 2 * BUF * sizeof(float));  // constant/call

    // 96 KB dynamic LDS -> exactly 1 WG/CU (256 WGs on 256 CUs, co-resident)
    const size_t scan_lds = 98304;
    hipFuncSetAttribute((const void*)rnn_scan_reg2,
                        hipFuncAttributeMaxDynamicSharedMemorySize, (int)scan_lds);

    // 1) xp0 = gather(emb,tokens) @ W_ih0^T + b_ih0 + b_hh0  -> buf
    gemm_bias<<<dim3(HID_ / 64, M_ / 64), 256, 0, stream>>>(
        emb, tokens, W_ih0, b_ih0, b_hh0, buf, M_, EMB_, HID_);

    // 2) layer-0 scan (in place on buf)
    rnn_scan_reg2<<<256, 512, scan_lds, stream>>>(W_hh0, buf);

    float* l1buf;   // buffer holding xp1 -> h1
    if (two_buf) {
        // 3a) full-grid xp1 GEMM into buf1 (no chunking, full GPU)
        gemm_bias<<<dim3(HID_ / 64, M_ / 64), 256, 0, stream>>>(
            buf, nullptr, W_ih1, b_ih1, b_hh1, buf1, M_, HID_, HID_);
        l1buf = buf1;
    } else {
        // 3b) fallback: chunk through d_out (¼-GPU launches, known-correct)
        for (int c = 0; c < 16; ++c) {
            const float* Ac = buf + (size_t)c * 1024 * HID_;
            gemm_bias<<<dim3(HID_ / 64, 1024 / 64), 256, 0, stream>>>(
                Ac, nullptr, W_ih1, b_ih1, b_hh1, tmp, 1024, HID_, HID_);
            copy4<<<1024, 256, 0, stream>>>(
                (const float4*)tmp, (float4*)(buf + (size_t)c * 1024 * HID_),
                1024 * HID_ / 4);
        }
        l1buf = buf;
    }

    // 4) layer-1 scan (in place)
    rnn_scan_reg2<<<256, 512, scan_lds, stream>>>(W_hh1, l1buf);

    // 5) out = h1 @ W_out^T + b_out (fully rewrites d_out)
    gemm_bias<<<dim3(LAB_ / 64, M_ / 64), 256, 0, stream>>>(
        l1buf, nullptr, W_out, b_out, nullptr, out, M_, HID_, LAB_);
}

// Round 6
// 5146.633 us; speedup vs baseline: 3.0922x; 1.7283x over previous
//
#include <hip/hip_runtime.h>
#include <math.h>

#define B_    32
#define S_    512
#define EMB_  512
#define HID_  1024
#define LAB_  64
#define M_    (B_ * S_)

// ---------------------------------------------------------------------------
// Fence-free h exchange: one 64-bit word per (batch,neuron) = (tag<<32)|bits.
// Relaxed agent atomics only — no acquire/release anywhere in the scan loop,
// so no per-step L2 writeback/invalidate. Tags: layer0 uses 1..512, layer1
// 513..1024; 0 (memset) and 0xAAAAAAAA (poison) never match. Depth-2 slots:
// a WG can only write tag t after every WG published t-1, which implies every
// WG finished reading slot t-2 (the slot being overwritten) — no hazard.
// ---------------------------------------------------------------------------
#define EX_SLOT (B_ * HID_)   // u64 words per slot (32768); 2 slots = 512 KB

__device__ __forceinline__ unsigned long long aload64(const unsigned long long* p) {
    return __hip_atomic_load((unsigned long long*)p, __ATOMIC_RELAXED,
                             __HIP_MEMORY_SCOPE_AGENT);
}
__device__ __forceinline__ void astore64(unsigned long long* p, unsigned long long v) {
    __hip_atomic_store(p, v, __ATOMIC_RELAXED, __HIP_MEMORY_SCOPE_AGENT);
}

// ---------------------------------------------------------------------------
// fp32 tiled GEMM with optional row-gather on A (unchanged, known-good):
//   C[m][n] = dot(Arow(m), W[n][:]) + bias[n] (+ bias2[n]),  W row-major [N,K]
// ---------------------------------------------------------------------------
__global__ __launch_bounds__(256) void gemm_bias(
    const float* __restrict__ A, const int* __restrict__ tokens,
    const float* __restrict__ W, const float* __restrict__ bias,
    const float* __restrict__ bias2, float* __restrict__ C,
    int M, int K, int N)
{
    __shared__ float As[64][17];
    __shared__ float Ws[64][17];

    const int tid = threadIdx.x;
    const int tx  = tid & 15;
    const int ty  = tid >> 4;
    const int n0  = blockIdx.x * 64;
    const int m0  = blockIdx.y * 64;

    const int lrow = tid >> 2;
    const int lk   = (tid & 3) << 2;

    const int arow_idx = tokens ? tokens[m0 + lrow] : (m0 + lrow);
    const float* __restrict__ arow = A + (size_t)arow_idx * K;
    const float* __restrict__ wrow = W + (size_t)(n0 + lrow) * K;

    float bs[4];
#pragma unroll
    for (int j = 0; j < 4; ++j) {
        int n = n0 + tx * 4 + j;
        bs[j] = bias[n] + (bias2 ? bias2[n] : 0.0f);
    }

    float acc[4][4] = {};

    for (int k0 = 0; k0 < K; k0 += 16) {
        const float4 av = *(const float4*)(arow + k0 + lk);
        const float4 wv = *(const float4*)(wrow + k0 + lk);
        __syncthreads();
        As[lrow][lk + 0] = av.x; As[lrow][lk + 1] = av.y;
        As[lrow][lk + 2] = av.z; As[lrow][lk + 3] = av.w;
        Ws[lrow][lk + 0] = wv.x; Ws[lrow][lk + 1] = wv.y;
        Ws[lrow][lk + 2] = wv.z; Ws[lrow][lk + 3] = wv.w;
        __syncthreads();

#pragma unroll
        for (int kk = 0; kk < 16; ++kk) {
            float a[4], b[4];
#pragma unroll
            for (int i = 0; i < 4; ++i) a[i] = As[ty * 4 + i][kk];
#pragma unroll
            for (int j = 0; j < 4; ++j) b[j] = Ws[tx * 4 + j][kk];
#pragma unroll
            for (int i = 0; i < 4; ++i)
#pragma unroll
                for (int j = 0; j < 4; ++j)
                    acc[i][j] += a[i] * b[j];
        }
    }

#pragma unroll
    for (int i = 0; i < 4; ++i) {
        const int m = m0 + ty * 4 + i;
        float4 v;
        v.x = acc[i][0] + bs[0];
        v.y = acc[i][1] + bs[1];
        v.z = acc[i][2] + bs[2];
        v.w = acc[i][3] + bs[3];
        *(float4*)(C + (size_t)m * N + n0 + tx * 4) = v;
    }
}

// ---------------------------------------------------------------------------
// Weight-stationary persistent scan, R6: same compute/layout as R5 (no spill,
// no bank conflicts) but the inter-WG exchange is fence-free tagged atomics.
// 256 WGs x 512 threads, 1 WG/CU (96 KB dyn LDS). WG = slice s (32 neurons)
// x batch group bg (4 batches, XCD-affine via wg&7). Weights in registers
// (4 neurons x 16 strided k). LDS h batch-transposed; 64-way split-k reduced
// through LDS. x: xp on entry, h on exit (plain stores; read next kernel).
// ---------------------------------------------------------------------------
#define RPAD 68   // red row stride in floats (272 B, b128-aligned)

__global__ __launch_bounds__(512, 2) void rnn_scan_tag(
    const float* __restrict__ Whh,          // [H][H] row-major
    float* __restrict__ x,                  // [B,S,H]
    unsigned long long* __restrict__ ex,    // [2][B_][HID_] tagged exchange
    unsigned tag0)                          // 1 (layer0) / 513 (layer1)
{
    extern __shared__ float smem[];
    float4* hl4 = (float4*)smem;              // 1024 float4 = 16 KB
    float*  red = smem + 4 * HID_;            // 128 x RPAD = 34.8 KB

    const int wg  = blockIdx.x;
    const int bg  = wg & 7;
    const int s   = wg >> 3;
    const int tid = threadIdx.x;     // 0..511
    const int j8  = tid >> 6;        // 0..7
    const int kg  = tid & 63;        // k = kg + 64q
    const int b0  = bg * 4;

    // --- weights into registers: 4 neurons x 16 strided k = 64 VGPRs ---
    float wreg[4][16];
    {
        const float* wb = Whh + (size_t)(s * 32 + j8 * 4) * HID_ + kg;
#pragma unroll
        for (int i = 0; i < 4; ++i)
#pragma unroll
            for (int q = 0; q < 16; ++q)
                wreg[i][q] = wb[(size_t)i * HID_ + q * 64];
    }

    for (int t = 0; t < S_; ++t) {
        __syncthreads();   // prev iter: hl4 readers + red readers done

        // ---- stage h_{t-1}: poll tagged words (relaxed; no fences) ----
        if (t > 0) {
            const unsigned wtag = tag0 + (unsigned)(t - 1);
            const unsigned long long* exs = ex + (size_t)((t - 1) & 1) * EX_SLOT;
#pragma unroll
            for (int c = 0; c < 2; ++c) {
                const int m = tid + 512 * c;   // k index, lane-contiguous
                unsigned long long w[4];
                int pend = 0xf;
                do {
#pragma unroll
                    for (int j = 0; j < 4; ++j) {
                        if (pend & (1 << j)) {
                            unsigned long long u =
                                aload64(exs + (size_t)(b0 + j) * HID_ + m);
                            if ((unsigned)(u >> 32) == wtag) {
                                w[j] = u;
                                pend &= ~(1 << j);
                            }
                        }
                    }
                } while (pend);
                float4 v;
                v.x = __uint_as_float((unsigned)w[0]);
                v.y = __uint_as_float((unsigned)w[1]);
                v.z = __uint_as_float((unsigned)w[2]);
                v.w = __uint_as_float((unsigned)w[3]);
                hl4[m] = v;                    // contiguous b128: conflict-free
            }
        } else {
#pragma unroll
            for (int c = 0; c < 2; ++c)
                hl4[tid + 512 * c] = make_float4(0.f, 0.f, 0.f, 0.f);
        }
        __syncthreads();

        // ---- partials: 4 neurons x 4 batches over 16 strided k ----
        float acc[4][4] = {};
#pragma unroll
        for (int q = 0; q < 16; ++q) {
            const float4 hv = hl4[kg + 64 * q];        // lane-contig: free
#pragma unroll
            for (int i = 0; i < 4; ++i) {
                const float w = wreg[i][q];
                acc[i][0] += w * hv.x;
                acc[i][1] += w * hv.y;
                acc[i][2] += w * hv.z;
                acc[i][3] += w * hv.w;
            }
        }

        // ---- write partials: red[o][kg], o = (j8*4+i)*4+b ----
#pragma unroll
        for (int i = 0; i < 4; ++i)
#pragma unroll
            for (int b = 0; b < 4; ++b)
                red[((j8 * 4 + i) * 4 + b) * RPAD + kg] = acc[i][b];
        __syncthreads();

        // ---- 2 waves reduce 64 partials each; publish h_t ----
        if (tid < 128) {
            const int o = tid;
            const float4* rp = (const float4*)(red + (size_t)o * RPAD);
            float4 r0 = rp[0], r1 = rp[1], r2 = rp[2],  r3 = rp[3];
            float4 r4 = rp[4], r5 = rp[5], r6 = rp[6],  r7 = rp[7];
            float4 r8 = rp[8], r9 = rp[9], ra = rp[10], rb = rp[11];
            float4 rc = rp[12], rd = rp[13], re = rp[14], rf = rp[15];
            float sum = (((r0.x+r0.y+r0.z+r0.w) + (r1.x+r1.y+r1.z+r1.w))
                       + ((r2.x+r2.y+r2.z+r2.w) + (r3.x+r3.y+r3.z+r3.w)))
                      + (((r4.x+r4.y+r4.z+r4.w) + (r5.x+r5.y+r5.z+r5.w))
                       + ((r6.x+r6.y+r6.z+r6.w) + (r7.x+r7.y+r7.z+r7.w)))
                      + (((r8.x+r8.y+r8.z+r8.w) + (r9.x+r9.y+r9.z+r9.w))
                       + ((ra.x+ra.y+ra.z+ra.w) + (rb.x+rb.y+rb.z+rb.w)))
                      + (((rc.x+rc.y+rc.z+rc.w) + (rd.x+rd.y+rd.z+rd.w))
                       + ((re.x+re.y+re.z+re.w) + (rf.x+rf.y+rf.z+rf.w)));
            const int jl = o >> 2, b = o & 3;
            const int k  = s * 32 + jl;
            float* px = x + ((size_t)(b0 + b) * S_ + t) * HID_ + k;
            const float hv = tanhf(*px + sum);   // xp read: own location
            *px = hv;                            // for next-layer GEMM
            const unsigned long long u =
                ((unsigned long long)(tag0 + (unsigned)t) << 32) |
                (unsigned long long)__float_as_uint(hv);
            astore64(ex + (size_t)(t & 1) * EX_SLOT + (size_t)(b0 + b) * HID_ + k, u);
        }
        // no trailing barrier / no flag: next iter's top barrier covers LDS
    }
}

__global__ __launch_bounds__(256) void copy4(
    const float4* __restrict__ src, float4* __restrict__ dst, int n4)
{
    const int i = blockIdx.x * 256 + threadIdx.x;
    if (i < n4) dst[i] = src[i];
}

extern "C" void kernel_launch(void* const* d_in, const int* in_sizes, int n_in,
                              void* d_out, int out_size, void* d_ws, size_t ws_size,
                              hipStream_t stream)
{
    const int*   tokens = (const int*)  d_in[0];
    const float* emb    = (const float*)d_in[1];
    const float* W_ih0  = (const float*)d_in[2];
    const float* W_hh0  = (const float*)d_in[3];
    const float* b_ih0  = (const float*)d_in[4];
    const float* b_hh0  = (const float*)d_in[5];
    const float* W_ih1  = (const float*)d_in[6];
    const float* W_hh1  = (const float*)d_in[7];
    const float* b_ih1  = (const float*)d_in[8];
    const float* b_hh1  = (const float*)d_in[9];
    const float* W_out  = (const float*)d_in[10];
    const float* b_out  = (const float*)d_in[11];
    float* out = (float*)d_out;

    const size_t BUF = (size_t)B_ * S_ * HID_;   // 64 MiB
    float* buf  = (float*)d_ws;
    float* buf1 = buf + BUF;                     // only if ws_size permits
    float* tmp  = (float*)d_out;                 // chunk bounce (fallback)
    unsigned long long* ex = (unsigned long long*)d_out;  // 512 KB exchange

    const int two_buf = (ws_size >= 2 * BUF * sizeof(float));  // constant/call

    // 96 KB dynamic LDS -> exactly 1 WG/CU (256 WGs co-resident on 256 CUs)
    const size_t scan_lds = 98304;
    hipFuncSetAttribute((const void*)rnn_scan_tag,
                        hipFuncAttributeMaxDynamicSharedMemorySize, (int)scan_lds);

    // 1) xp0 = gather(emb,tokens) @ W_ih0^T + b_ih0 + b_hh0  -> buf
    gemm_bias<<<dim3(HID_ / 64, M_ / 64), 256, 0, stream>>>(
        emb, tokens, W_ih0, b_ih0, b_hh0, buf, M_, EMB_, HID_);

    // 2) layer-0 scan (in place on buf; tags 1..512)
    rnn_scan_tag<<<256, 512, scan_lds, stream>>>(W_hh0, buf, ex, 1u);

    float* l1buf;
    if (two_buf) {
        // 3a) full-grid xp1 GEMM into buf1
        gemm_bias<<<dim3(HID_ / 64, M_ / 64), 256, 0, stream>>>(
            buf, nullptr, W_ih1, b_ih1, b_hh1, buf1, M_, HID_, HID_);
        l1buf = buf1;
    } else {
        // 3b) fallback: chunk through d_out (overwrites ex region — dead now)
        for (int c = 0; c < 16; ++c) {
            const float* Ac = buf + (size_t)c * 1024 * HID_;
            gemm_bias<<<dim3(HID_ / 64, 1024 / 64), 256, 0, stream>>>(
                Ac, nullptr, W_ih1, b_ih1, b_hh1, tmp, 1024, HID_, HID_);
            copy4<<<1024, 256, 0, stream>>>(
                (const float4*)tmp, (float4*)(buf + (size_t)c * 1024 * HID_),
                1024 * HID_ / 4);
        }
        l1buf = buf;
    }

    // 4) layer-1 scan (tags 513..1024 — no aliasing with layer 0 leftovers)
    rnn_scan_tag<<<256, 512, scan_lds, stream>>>(W_hh1, l1buf, ex, 513u);

    // 5) out = h1 @ W_out^T + b_out (fully rewrites d_out incl. ex region)
    gemm_bias<<<dim3(LAB_ / 64, M_ / 64), 256, 0, stream>>>(
        l1buf, nullptr, W_out, b_out, nullptr, out, M_, HID_, LAB_);
}